// Round 1
// baseline (291.431 us; speedup 1.0000x reference)
//
#include <hip/hip_runtime.h>

// Bilinear warp (grid_sample align_corners=True, padding_mode='border').
// src: [B=8, C=16, H=512, W=512] f32, flow: [B, 2, H, W] f32 -> out [B,C,H,W] f32.
// Normalize/unnormalize in the reference cancels exactly: py = clip(h+flow0, 0, H-1).

#define BB 8
#define CC 16
#define HH 512
#define WW 512

__global__ __launch_bounds__(256) void warp_kernel(
    const float* __restrict__ src,
    const float* __restrict__ flow,
    float* __restrict__ out)
{
    const int HW = HH * WW;
    int idx = blockIdx.x * blockDim.x + threadIdx.x;   // pixel index in [0, B*H*W)
    if (idx >= BB * HW) return;

    int b  = idx >> 18;          // / (512*512)
    int hw = idx & (HW - 1);
    int h  = hw >> 9;            // / 512
    int w  = hw & (WW - 1);

    const float* fb = flow + (size_t)b * 2 * HW;
    float f0 = fb[hw];          // y displacement
    float f1 = fb[HW + hw];     // x displacement

    float py = fminf(fmaxf((float)h + f0, 0.0f), (float)(HH - 1));
    float px = fminf(fmaxf((float)w + f1, 0.0f), (float)(WW - 1));

    float y0f = floorf(py);
    float x0f = floorf(px);
    float wy = py - y0f;
    float wx = px - x0f;

    int y0 = (int)y0f;
    int x0 = (int)x0f;
    int y1 = min(y0 + 1, HH - 1);
    int x1 = min(x0 + 1, WW - 1);

    float w00 = (1.0f - wy) * (1.0f - wx);
    float w01 = (1.0f - wy) * wx;
    float w10 = wy * (1.0f - wx);
    float w11 = wy * wx;

    int o00 = y0 * WW + x0;
    int o01 = y0 * WW + x1;
    int o10 = y1 * WW + x0;
    int o11 = y1 * WW + x1;

    const float* sb = src + (size_t)b * CC * HW;
    float*       ob = out + (size_t)b * CC * HW;

    #pragma unroll
    for (int c = 0; c < CC; ++c) {
        const float* sc = sb + c * HW;
        float v = sc[o00] * w00 + sc[o01] * w01
                + sc[o10] * w10 + sc[o11] * w11;
        ob[c * HW + hw] = v;
    }
}

extern "C" void kernel_launch(void* const* d_in, const int* in_sizes, int n_in,
                              void* d_out, int out_size, void* d_ws, size_t ws_size,
                              hipStream_t stream) {
    const float* src  = (const float*)d_in[0];
    const float* flow = (const float*)d_in[1];
    float* out = (float*)d_out;

    const int n_pix = BB * HH * WW;          // 2,097,152
    dim3 block(256);
    dim3 grid((n_pix + 255) / 256);          // 8192 blocks
    warp_kernel<<<grid, block, 0, stream>>>(src, flow, out);
}